// Round 3
// baseline (27.952 us; speedup 1.0000x reference)
//
#include <hip/hip_runtime.h>

#define MARGIN 0.5f
#define NROWS 4096
#define D 128
#define WAVES_PER_BLOCK 4                       // 1 wave per row
#define NBLOCKS (NROWS / WAVES_PER_BLOCK)       // 1024

// Single fused kernel:
//  - per wave: ballot-compact neg logits / pos constants into wave-private LDS
//  - inner loop: float4 broadcast reads over compacted negatives
//  - per-block partial (sum of row means, valid count) -> agent-scope store
//  - ticket atomicAdd; last-arriving block reduces the 1024 partials in
//    fixed order (deterministic) and writes the scalar.
__global__ __launch_bounds__(256) void mrl_fused_kernel(
    const float* __restrict__ logits,
    const int*   __restrict__ labels,
    float*        __restrict__ psum,     // [NBLOCKS]
    float*        __restrict__ pval,     // [NBLOCKS]
    unsigned int* __restrict__ ticket,   // [1] — never reset; modulo trick
    float*        __restrict__ out)
{
    const int wave = threadIdx.x >> 6;
    const int lane = threadIdx.x & 63;
    const int row  = blockIdx.x * WAVES_PER_BLOCK + wave;

    __shared__ float s_neg[WAVES_PER_BLOCK][132];   // compacted negs + pad
    __shared__ float s_pos[WAVES_PER_BLOCK][132];   // compacted (MARGIN - pos)
    __shared__ float sb_sum[WAVES_PER_BLOCK];
    __shared__ float sb_val[WAVES_PER_BLOCK];
    __shared__ int   s_last;

    const float* lrow   = logits + (size_t)row * D;
    const int*   labrow = labels + (size_t)row * D;

    const int i0 = lane * 2;
    float2 lv = *reinterpret_cast<const float2*>(lrow + i0);
    int2   bv = *reinterpret_cast<const int2*>(labrow + i0);

    const bool n0 = (bv.x == 0), n1 = (bv.y == 0);
    const bool p0 = (bv.x > 0),  p1 = (bv.y > 0);

    const unsigned long long mn0 = __ballot(n0);
    const unsigned long long mn1 = __ballot(n1);
    const unsigned long long mp0 = __ballot(p0);
    const unsigned long long mp1 = __ballot(p1);
    const unsigned long long below = (1ull << lane) - 1ull;

    const int nneg = __popcll(mn0) + __popcll(mn1);
    const int npos = __popcll(mp0) + __popcll(mp1);

    if (n0) s_neg[wave][__popcll(mn0 & below)]                 = lv.x;
    if (n1) s_neg[wave][__popcll(mn0) + __popcll(mn1 & below)] = lv.y;
    if (p0) s_pos[wave][__popcll(mp0 & below)]                 = MARGIN - lv.x;
    if (p1) s_pos[wave][__popcll(mp0) + __popcll(mp1 & below)] = MARGIN - lv.y;

    // pad negs to x4 with -BIG so fmax(neg + c, 0) == 0
    if (lane < 4) s_neg[wave][nneg + lane] = -3.0e38f;

    // wave-private LDS: lockstep wave64 + in-order LDS pipe; just stop the
    // compiler from reordering the reads above the writes.
    __builtin_amdgcn_wave_barrier();

    const int nneg4 = (nneg + 3) >> 2;
    const float4* vp = reinterpret_cast<const float4*>(s_neg[wave]);

    float acc = 0.f;
    for (int p = lane; p < npos; p += 64) {
        const float c = s_pos[wave][p];
        float a = 0.f;
#pragma unroll 2
        for (int q = 0; q < nneg4; ++q) {
            float4 v = vp[q];                 // broadcast read, conflict-free
            a += fmaxf(v.x + c, 0.f);
            a += fmaxf(v.y + c, 0.f);
            a += fmaxf(v.z + c, 0.f);
            a += fmaxf(v.w + c, 0.f);
        }
        acc += a;
    }

    for (int off = 32; off > 0; off >>= 1)
        acc += __shfl_xor(acc, off);

    if (lane == 0) {
        const int cnt = npos * nneg;
        sb_sum[wave] = (cnt > 0) ? acc / (float)cnt : 0.f;
        sb_val[wave] = (cnt > 0) ? 1.f : 0.f;
    }
    __syncthreads();

    if (threadIdx.x == 0) {
        const float S = sb_sum[0] + sb_sum[1] + sb_sum[2] + sb_sum[3];
        const float V = sb_val[0] + sb_val[1] + sb_val[2] + sb_val[3];
        __hip_atomic_store(&psum[blockIdx.x], S, __ATOMIC_RELAXED, __HIP_MEMORY_SCOPE_AGENT);
        __hip_atomic_store(&pval[blockIdx.x], V, __ATOMIC_RELAXED, __HIP_MEMORY_SCOPE_AGENT);
        const unsigned int old =
            __hip_atomic_fetch_add(ticket, 1u, __ATOMIC_ACQ_REL, __HIP_MEMORY_SCOPE_AGENT);
        // exactly one block per launch satisfies this, regardless of the
        // (poisoned, never-reset) starting value: each launch adds NBLOCKS.
        s_last = (((old + 1u) & (NBLOCKS - 1u)) == 0u) ? 1 : 0;
    }
    __syncthreads();
    if (!s_last) return;

    // ---- final reduce (last block only), fixed order -> deterministic ----
    float s = 0.f, v = 0.f;
    for (int i = threadIdx.x; i < NBLOCKS; i += 256) {
        s += __hip_atomic_load(&psum[i], __ATOMIC_RELAXED, __HIP_MEMORY_SCOPE_AGENT);
        v += __hip_atomic_load(&pval[i], __ATOMIC_RELAXED, __HIP_MEMORY_SCOPE_AGENT);
    }
    for (int off = 32; off > 0; off >>= 1) {
        s += __shfl_xor(s, off);
        v += __shfl_xor(v, off);
    }
    __syncthreads();                  // reuse sb_sum/sb_val safely
    if (lane == 0) { sb_sum[wave] = s; sb_val[wave] = v; }
    __syncthreads();
    if (threadIdx.x == 0) {
        const float S = sb_sum[0] + sb_sum[1] + sb_sum[2] + sb_sum[3];
        const float V = sb_val[0] + sb_val[1] + sb_val[2] + sb_val[3];
        out[0] = (V > 0.f) ? S / V : 0.f;
    }
}

extern "C" void kernel_launch(void* const* d_in, const int* in_sizes, int n_in,
                              void* d_out, int out_size, void* d_ws, size_t ws_size,
                              hipStream_t stream) {
    const float* logits = (const float*)d_in[0];
    const int*   labels = (const int*)d_in[1];
    float* out = (float*)d_out;
    float* ws  = (float*)d_ws;
    // ws layout: [0..NBLOCKS) psum | [NBLOCKS..2N) pval | ticket (uint) at 2N
    float* psum = ws;
    float* pval = ws + NBLOCKS;
    unsigned int* ticket = (unsigned int*)(ws + 2 * NBLOCKS);

    mrl_fused_kernel<<<NBLOCKS, 256, 0, stream>>>(logits, labels, psum, pval, ticket, out);
}

// Round 4
// 12.176 us; speedup vs baseline: 2.2957x; 2.2957x over previous
//
#include <hip/hip_runtime.h>

#define MARGIN 0.5f
#define NROWS 4096
#define D 128
#define BLK_WAVES 16                       // 1024 threads, 1 wave per row
#define NBLK (NROWS / BLK_WAVES)           // 256 blocks

// Kernel 1: 256 blocks x 1024 threads; one wave per row.
//  - ballot-compact negative logits / positive constants into wave-private LDS
//  - float4 broadcast reads over compacted negatives
//  - wave reduce -> per-row mean; block LDS reduce -> one float2 partial
__global__ __launch_bounds__(1024) void mrl_row_kernel(
    const float* __restrict__ logits,
    const int*   __restrict__ labels,
    float2* __restrict__ partial)          // [NBLK] = (sum of row means, valid count)
{
    const int wave = threadIdx.x >> 6;     // 0..15
    const int lane = threadIdx.x & 63;
    const int row  = blockIdx.x * BLK_WAVES + wave;

    __shared__ float  s_neg[BLK_WAVES][132];
    __shared__ float  s_pos[BLK_WAVES][132];
    __shared__ float2 sw[BLK_WAVES];

    const float* lrow   = logits + (size_t)row * D;
    const int*   labrow = labels + (size_t)row * D;

    const int i0 = lane * 2;
    float2 lv = *reinterpret_cast<const float2*>(lrow + i0);
    int2   bv = *reinterpret_cast<const int2*>(labrow + i0);

    const bool n0 = (bv.x == 0), n1 = (bv.y == 0);
    const bool p0 = (bv.x > 0),  p1 = (bv.y > 0);

    const unsigned long long mn0 = __ballot(n0);
    const unsigned long long mn1 = __ballot(n1);
    const unsigned long long mp0 = __ballot(p0);
    const unsigned long long mp1 = __ballot(p1);
    const unsigned long long below = (1ull << lane) - 1ull;

    const int nneg = __popcll(mn0) + __popcll(mn1);
    const int npos = __popcll(mp0) + __popcll(mp1);

    if (n0) s_neg[wave][__popcll(mn0 & below)]                 = lv.x;
    if (n1) s_neg[wave][__popcll(mn0) + __popcll(mn1 & below)] = lv.y;
    if (p0) s_pos[wave][__popcll(mp0 & below)]                 = MARGIN - lv.x;
    if (p1) s_pos[wave][__popcll(mp0) + __popcll(mp1 & below)] = MARGIN - lv.y;

    // pad negs to x4 with -BIG so fmax(neg + c, 0) == 0
    if (lane < 4) s_neg[wave][nneg + lane] = -3.0e38f;

    // wave-private LDS region: wave64 lockstep + in-order LDS pipe; only
    // stop compiler reordering of the reads above the writes.
    __builtin_amdgcn_wave_barrier();

    const int nneg4 = (nneg + 3) >> 2;
    const float4* vp = reinterpret_cast<const float4*>(s_neg[wave]);

    float acc = 0.f;
    for (int p = lane; p < npos; p += 64) {
        const float c = s_pos[wave][p];
        float a = 0.f;
#pragma unroll 2
        for (int q = 0; q < nneg4; ++q) {
            float4 v = vp[q];              // broadcast read, conflict-free
            a += fmaxf(v.x + c, 0.f);
            a += fmaxf(v.y + c, 0.f);
            a += fmaxf(v.z + c, 0.f);
            a += fmaxf(v.w + c, 0.f);
        }
        acc += a;
    }

    for (int off = 32; off > 0; off >>= 1)
        acc += __shfl_xor(acc, off);

    if (lane == 0) {
        const int cnt = npos * nneg;
        sw[wave] = (cnt > 0) ? make_float2(acc / (float)cnt, 1.f)
                             : make_float2(0.f, 0.f);
    }
    __syncthreads();

    if (wave == 0) {
        float2 t = (lane < BLK_WAVES) ? sw[lane] : make_float2(0.f, 0.f);
        // lanes 0..15 self-contained under xor offsets < 16
        for (int off = 8; off > 0; off >>= 1) {
            t.x += __shfl_xor(t.x, off);
            t.y += __shfl_xor(t.y, off);
        }
        if (lane == 0) partial[blockIdx.x] = t;
    }
}

// Kernel 2: one block, 256 threads, single coalesced float2 round.
__global__ __launch_bounds__(256) void mrl_reduce_kernel(
    const float2* __restrict__ partial,
    float* __restrict__ out)
{
    float2 t = partial[threadIdx.x];       // 256 partials, one per thread
    for (int off = 32; off > 0; off >>= 1) {
        t.x += __shfl_xor(t.x, off);
        t.y += __shfl_xor(t.y, off);
    }
    __shared__ float2 sw[4];
    const int wave = threadIdx.x >> 6;
    const int lane = threadIdx.x & 63;
    if (lane == 0) sw[wave] = t;
    __syncthreads();
    if (threadIdx.x == 0) {
        const float S = sw[0].x + sw[1].x + sw[2].x + sw[3].x;
        const float V = sw[0].y + sw[1].y + sw[2].y + sw[3].y;
        out[0] = (V > 0.f) ? S / V : 0.f;
    }
}

extern "C" void kernel_launch(void* const* d_in, const int* in_sizes, int n_in,
                              void* d_out, int out_size, void* d_ws, size_t ws_size,
                              hipStream_t stream) {
    const float* logits = (const float*)d_in[0];
    const int*   labels = (const int*)d_in[1];
    float* out = (float*)d_out;
    float2* partial = (float2*)d_ws;       // 256 * 8 B

    mrl_row_kernel<<<NBLK, 1024, 0, stream>>>(logits, labels, partial);
    mrl_reduce_kernel<<<1, 256, 0, stream>>>(partial, out);
}